// Round 17
// baseline (201.310 us; speedup 1.0000x reference)
//
#include <hip/hip_runtime.h>

typedef __bf16 bf16;
typedef __bf16 bf16x4 __attribute__((ext_vector_type(4)));
typedef __bf16 bf16x8 __attribute__((ext_vector_type(8)));
typedef float f32x4 __attribute__((ext_vector_type(4)));
typedef float f32x16 __attribute__((ext_vector_type(16)));

#define MFMA16(a, b, c) __builtin_amdgcn_mfma_f32_16x16x32_bf16(a, b, c, 0, 0, 0)
#define MFMA32(a, b, c) __builtin_amdgcn_mfma_f32_32x32x16_bf16(a, b, c, 0, 0, 0)

// async global->LDS DMA, 16B/lane; LDS dest = wave-uniform base + lane*16.
__device__ __forceinline__ void lds_load16(void* lds, const void* g) {
  __builtin_amdgcn_global_load_lds(
      (const __attribute__((address_space(1))) unsigned int*)g,
      (__attribute__((address_space(3))) unsigned int*)lds, 16, 0, 0);
}

// fp32 -> bf16 bulk convert, all three tensors in one launch.
__global__ void cvt3(const float* __restrict__ x, const float* __restrict__ qw,
                     const float* __restrict__ ow, bf16* __restrict__ xb,
                     bf16* __restrict__ qwb, bf16* __restrict__ owb) {
  const int i = blockIdx.x * blockDim.x + threadIdx.x;  // 0..2097151
  const float* src;
  bf16* dst;
  int k;
  if (i < 1048576) {
    src = x; dst = xb; k = i;
  } else if (i < 1048576 + 786432) {
    src = qw; dst = qwb; k = i - 1048576;
  } else {
    src = ow; dst = owb; k = i - (1048576 + 786432);
  }
  const float4 v = ((const float4*)src)[k];
  bf16x4 o;
  o[0] = (bf16)v.x; o[1] = (bf16)v.y; o[2] = (bf16)v.z; o[3] = (bf16)v.w;
  ((bf16x4*)dst)[k] = o;
}

// QKV GEMM — r17: inner loop on v_mfma_f32_32x32x16_bf16 (16 MFMA/iter vs 32,
// same 16 ds_read_b128; frees issue slots, +15% MFMA ceiling per m06).
// A-frag: A[m=lane&31][k=(lane>>5)*8+j] (extrapolated from verified 16x16 map);
// C/D: col=lane&31, row=(reg&3)+8*(reg>>2)+4*(lane>>5)  [HW-verified m74/m101].
//   col<1024  -> Qb[t][col], PRE-SCALED by 0.125*log2(e)
//   col<2048  -> KF fragment-native (attn A-frag = base + lane*16B)
//   col>=2048 -> VF fragment-native, bf16x4-packed along t
__global__ __launch_bounds__(256, 2) void gemm_qkv(
    const bf16* __restrict__ A, const bf16* __restrict__ B,
    const float* __restrict__ bias, bf16* __restrict__ Qb,
    bf16* __restrict__ KF, bf16* __restrict__ VF) {
  const int K = 1024;
  __shared__ bf16 As[128][64];
  __shared__ bf16 Bs[128][64];
  const int tid = threadIdx.x;
  const int w = tid >> 6, lane = tid & 63;
  const int l31 = lane & 31, lh = lane >> 5;  // 32x32 operand coords
  const int lr = lane >> 3;       // row within 8-row DMA chunk
  const int lc = (lane & 7) * 8;  // elem col within 64-col tile
  const int blk = blockIdx.x;     // 0..767 linear
  const int xslot = blk & 7, rest = blk >> 3;  // rest 0..95
  const int bm = xslot * 4 + (rest & 3);       // 0..31
  const int bn = rest >> 2;                    // 0..23
  const int wm = (w >> 1) * 64, wn = (w & 1) * 64;

  const bf16* Abase = A + (size_t)(bm * 128) * K;
  const bf16* Bbase = B + (size_t)(bn * 128) * K;

  f32x16 acc[2][2] = {};

  for (int k0 = 0; k0 < K; k0 += 64) {
#pragma unroll
    for (int c = 0; c < 4; ++c) {
      const int row = w * 32 + c * 8;
      lds_load16(&As[row][0], Abase + (size_t)(row + lr) * K + k0 + lc);
      lds_load16(&Bs[row][0], Bbase + (size_t)(row + lr) * K + k0 + lc);
    }
    __syncthreads();
#pragma unroll
    for (int ks = 0; ks < 4; ++ks) {  // K-step of 16
      bf16x8 am[2], bnf[2];
#pragma unroll
      for (int i = 0; i < 2; ++i)
        am[i] = *(const bf16x8*)&As[wm + i * 32 + l31][ks * 16 + lh * 8];
#pragma unroll
      for (int j = 0; j < 2; ++j)
        bnf[j] = *(const bf16x8*)&Bs[wn + j * 32 + l31][ks * 16 + lh * 8];
#pragma unroll
      for (int i = 0; i < 2; ++i)
#pragma unroll
        for (int j = 0; j < 2; ++j)
          acc[i][j] = MFMA32(am[i], bnf[j], acc[i][j]);
    }
    __syncthreads();
  }

  // epilogue: C/D col=lane&31; row=(reg&3)+8*(reg>>2)+4*lh, reg=g*4+r
#pragma unroll
  for (int j = 0; j < 2; ++j) {
    const int gcol = bn * 128 + wn + j * 32 + l31;
    const float bv = bias[gcol];
#pragma unroll
    for (int i = 0; i < 2; ++i) {
#pragma unroll
      for (int g = 0; g < 4; ++g) {
        const int t0 = bm * 128 + wm + i * 32 + g * 8 + lh * 4;  // +r, r=0..3
        if (gcol < 1024) {
#pragma unroll
          for (int r = 0; r < 4; ++r)
            Qb[(size_t)(t0 + r) * 1024 + gcol] =
                (bf16)((acc[i][j][g * 4 + r] + bv) * 0.18033688f);
        } else if (gcol < 2048) {
          const int dhl = gcol - 1024;  // 0..1023
          const int hh = dhl >> 6, dh = dhl & 63;
          const int tl = t0 & 2047, bb = t0 >> 11;
          const size_t frag = ((size_t)(bb * 16 + hh) * 32 + (tl >> 6)) * 8 +
                              ((tl & 63) >> 4) * 2 + (dh >> 5);
          bf16* p = &KF[frag * 512 +
                        (size_t)(((dh >> 3) & 3) * 16 + (tl & 15)) * 8 +
                        (dh & 7)];
#pragma unroll
          for (int r = 0; r < 4; ++r)
            p[r * 8] = (bf16)(acc[i][j][g * 4 + r] + bv);
        } else {
          const int dhl = gcol - 2048;
          const int hh = dhl >> 6, dh = dhl & 63;
          const int tl = t0 & 2047, bb = t0 >> 11;
          const size_t frag = ((size_t)(bb * 16 + hh) * 32 + (tl >> 6)) * 8 +
                              (dh >> 4) * 2 + ((tl & 63) >> 5);
          bf16x4 pv;
#pragma unroll
          for (int r = 0; r < 4; ++r) pv[r] = (bf16)(acc[i][j][g * 4 + r] + bv);
          *(bf16x4*)&VF[frag * 512 +
                        (size_t)(((tl & 31) >> 3) * 16 + (dh & 15)) * 8 +
                        (tl & 7)] = pv;
        }
      }
    }
  }
}

// Out-proj GEMM, 64x128 tile (UNCHANGED 16x16 — control for the 32x32 test).
__global__ __launch_bounds__(256, 2) void gemm_out(
    const bf16* __restrict__ A, const bf16* __restrict__ B,
    const float* __restrict__ bias, float* __restrict__ Cf) {
  __shared__ bf16 As[64][64];
  __shared__ bf16 Bs[128][64];
  const int tid = threadIdx.x;
  const int w = tid >> 6, lane = tid & 63;
  const int l15 = lane & 15, quad = lane >> 4;
  const int lr = lane >> 3, lc = (lane & 7) * 8;
  const int blk = blockIdx.x;  // 0..511 linear
  const int xslot = blk & 7, rest = blk >> 3;  // rest 0..63
  const int bm = xslot * 8 + (rest & 7);       // 0..63
  const int bn = rest >> 3;                    // 0..7

  const bf16* Abase = A + (size_t)(bm * 64) * 1024;
  const bf16* Bbase = B + (size_t)(bn * 128) * 1024;

  f32x4 acc[4][2] = {};

  for (int k0 = 0; k0 < 1024; k0 += 64) {
#pragma unroll
    for (int c = 0; c < 2; ++c) {
      const int row = w * 16 + c * 8;
      lds_load16(&As[row][0], Abase + (size_t)(row + lr) * 1024 + k0 + lc);
    }
#pragma unroll
    for (int c = 0; c < 4; ++c) {
      const int row = w * 32 + c * 8;
      lds_load16(&Bs[row][0], Bbase + (size_t)(row + lr) * 1024 + k0 + lc);
    }
    __syncthreads();
#pragma unroll
    for (int kk = 0; kk < 64; kk += 32) {
      bf16x8 am[4], bnf[2];
#pragma unroll
      for (int i = 0; i < 4; ++i)
        am[i] = *(const bf16x8*)&As[i * 16 + l15][kk + quad * 8];
#pragma unroll
      for (int j = 0; j < 2; ++j)
        bnf[j] = *(const bf16x8*)&Bs[w * 32 + j * 16 + l15][kk + quad * 8];
#pragma unroll
      for (int i = 0; i < 4; ++i)
#pragma unroll
        for (int j = 0; j < 2; ++j)
          acc[i][j] = MFMA16(am[i], bnf[j], acc[i][j]);
    }
    __syncthreads();
  }

#pragma unroll
  for (int j = 0; j < 2; ++j) {
    const int gcol = bn * 128 + w * 32 + j * 16 + l15;
    const float bv = bias[gcol];
#pragma unroll
    for (int i = 0; i < 4; ++i)
#pragma unroll
      for (int r = 0; r < 4; ++r) {
        const int grow = bm * 64 + i * 16 + quad * 4 + r;
        Cf[(size_t)grow * 1024 + gcol] = acc[i][j][r] + bv;
      }
  }
}

// Flash attention v9 (FROZEN — structural plateau at ~52 us).
__global__ __launch_bounds__(256, 2) void attn(const bf16* __restrict__ Qb,
                                               const bf16* __restrict__ KF,
                                               const bf16* __restrict__ VF,
                                               bf16* __restrict__ CTX) {
  __shared__ bf16 Kb[2][4096];  // ping-pong K fragment tiles (8 KB each)
  __shared__ bf16 Vb[2][4096];  // ping-pong V fragment tiles
  __shared__ bf16 Ps[128][72];  // [q][key], wave-private 32-row bands
  const int tid = threadIdx.x, w = tid >> 6, lane = tid & 63;
  const int l15 = lane & 15, quad = lane >> 4;
  const int blk = blockIdx.x;
  const int slot = blk & 7, grp = blk >> 3;
  const int qt = grp & 15, bh = (grp >> 4) * 8 + slot;  // bh 0..31
  const int h = bh & 15, b = bh >> 4;
  const int q0 = qt * 128;

  const bf16* qrow0 =
      Qb + (size_t)(b * 2048 + q0 + w * 32 + l15) * 1024 + h * 64;
  const bf16* qrow1 = qrow0 + (size_t)16 * 1024;
  const bf16x8 bq0a = *(const bf16x8*)&qrow0[quad * 8];
  const bf16x8 bq0b = *(const bf16x8*)&qrow0[32 + quad * 8];
  const bf16x8 bq1a = *(const bf16x8*)&qrow1[quad * 8];
  const bf16x8 bq1b = *(const bf16x8*)&qrow1[32 + quad * 8];

  const bf16* kfs = KF + (size_t)(b * 16 + h) * 131072;
  const bf16* vfs = VF + (size_t)(b * 16 + h) * 131072;
  const int so = w * 1024;

#pragma unroll
  for (int c = 0; c < 2; ++c) {
    lds_load16(&Kb[0][so + c * 512], kfs + so + c * 512 + lane * 8);
    lds_load16(&Vb[0][so + c * 512], vfs + so + c * 512 + lane * 8);
  }

  float l_run[2] = {0.f, 0.f};
  f32x4 o[2][4] = {};

  for (int kt6 = 0; kt6 < 32; ++kt6) {
    const int cur = kt6 & 1;
    const bf16* kcur = Kb[cur];
    const bf16* vcur = Vb[cur];
    __syncthreads();

    if (kt6 < 31) {
      const size_t nb = (size_t)(kt6 + 1) * 4096;
#pragma unroll
      for (int c = 0; c < 2; ++c) {
        lds_load16(&Kb[cur ^ 1][so + c * 512], kfs + nb + so + c * 512 + lane * 8);
        lds_load16(&Vb[cur ^ 1][so + c * 512], vfs + nb + so + c * 512 + lane * 8);
      }
    }

    f32x4 s[2][4] = {};
#pragma unroll
    for (int k2 = 0; k2 < 2; ++k2)
#pragma unroll
      for (int j = 0; j < 4; ++j) {
        const bf16x8 ak = *(const bf16x8*)&kcur[(j * 2 + k2) * 512 + lane * 8];
        s[0][j] = MFMA16(ak, k2 ? bq0b : bq0a, s[0][j]);
        s[1][j] = MFMA16(ak, k2 ? bq1b : bq1a, s[1][j]);
      }

#pragma unroll
    for (int i = 0; i < 2; ++i) {
      float sum = 0.f;
#pragma unroll
      for (int j = 0; j < 4; ++j) {
        bf16x4 pk;
#pragma unroll
        for (int r = 0; r < 4; ++r) {
          const float p = __builtin_amdgcn_exp2f(s[i][j][r]);
          sum += p;
          pk[r] = (bf16)p;
        }
        *(bf16x4*)&Ps[w * 32 + i * 16 + l15][j * 16 + quad * 4] = pk;
      }
      l_run[i] += sum;
    }

#pragma unroll
    for (int k2 = 0; k2 < 2; ++k2) {
      const bf16x8 bp0 = *(const bf16x8*)&Ps[w * 32 + l15][k2 * 32 + quad * 8];
      const bf16x8 bp1 =
          *(const bf16x8*)&Ps[w * 32 + 16 + l15][k2 * 32 + quad * 8];
#pragma unroll
      for (int j = 0; j < 4; ++j) {
        const bf16x8 av = *(const bf16x8*)&vcur[(j * 2 + k2) * 512 + lane * 8];
        o[0][j] = MFMA16(av, bp0, o[0][j]);
        o[1][j] = MFMA16(av, bp1, o[1][j]);
      }
    }
  }

#pragma unroll
  for (int i = 0; i < 2; ++i) {
    l_run[i] += __shfl_xor(l_run[i], 16);
    l_run[i] += __shfl_xor(l_run[i], 32);
  }

#pragma unroll
  for (int i = 0; i < 2; ++i) {
    const float inv = 1.f / l_run[i];
    bf16* crow =
        CTX + (size_t)(b * 2048 + q0 + w * 32 + i * 16 + l15) * 1024 + h * 64;
#pragma unroll
    for (int j = 0; j < 4; ++j) {
      bf16x4 ov;
#pragma unroll
      for (int r = 0; r < 4; ++r) ov[r] = (bf16)(o[i][j][r] * inv);
      *(bf16x4*)&crow[j * 16 + quad * 4] = ov;
    }
  }
}

extern "C" void kernel_launch(void* const* d_in, const int* in_sizes, int n_in,
                              void* d_out, int out_size, void* d_ws,
                              size_t ws_size, hipStream_t stream) {
  const float* x = (const float*)d_in[0];      // [2,2048,1024] fp32
  const float* qkv_w = (const float*)d_in[1];  // [3072,1024] fp32
  const float* qkv_b = (const float*)d_in[2];  // [3072] fp32
  const float* out_w = (const float*)d_in[3];  // [1024,1024] fp32
  const float* out_b = (const float*)d_in[4];  // [1024] fp32
  float* out = (float*)d_out;                  // [2,2048,1024] fp32

  // ws (bf16): xb 8MB | wqkv 6MB | wout 2MB | qb 8 | KF 8 | VF 8 | ctx 8 = 48MB
  bf16* xb = (bf16*)d_ws;                   // [4096][1024]
  bf16* wqkv = xb + (size_t)4096 * 1024;    // [3072][1024]
  bf16* wout = wqkv + (size_t)3072 * 1024;  // [1024][1024]
  bf16* qb = wout + (size_t)1024 * 1024;    // [4096][1024], x0.125*log2e
  bf16* kf = qb + (size_t)4096 * 1024;      // frag-native K
  bf16* vf = kf + (size_t)4096 * 1024;      // frag-native V^T
  bf16* ctx = vf + (size_t)4096 * 1024;     // [4096][1024]

  cvt3<<<2097152 / 256, 256, 0, stream>>>(x, qkv_w, out_w, xb, wqkv, wout);

  gemm_qkv<<<768, 256, 0, stream>>>(xb, wqkv, qkv_b, qb, kf, vf);
  attn<<<512, 256, 0, stream>>>(qb, kf, vf, ctx);
  gemm_out<<<512, 256, 0, stream>>>(ctx, wout, out_b, out);
}

// Round 18
// 181.174 us; speedup vs baseline: 1.1111x; 1.1111x over previous
//
#include <hip/hip_runtime.h>

typedef __bf16 bf16;
typedef __bf16 bf16x4 __attribute__((ext_vector_type(4)));
typedef __bf16 bf16x8 __attribute__((ext_vector_type(8)));
typedef float f32x4 __attribute__((ext_vector_type(4)));

#define MFMA16(a, b, c) __builtin_amdgcn_mfma_f32_16x16x32_bf16(a, b, c, 0, 0, 0)

// async global->LDS DMA, 16B/lane; LDS dest = wave-uniform base + lane*16.
__device__ __forceinline__ void lds_load16(void* lds, const void* g) {
  __builtin_amdgcn_global_load_lds(
      (const __attribute__((address_space(1))) unsigned int*)g,
      (__attribute__((address_space(3))) unsigned int*)lds, 16, 0, 0);
}

// fp32 -> bf16 bulk convert, all three tensors in one launch.
__global__ void cvt3(const float* __restrict__ x, const float* __restrict__ qw,
                     const float* __restrict__ ow, bf16* __restrict__ xb,
                     bf16* __restrict__ qwb, bf16* __restrict__ owb) {
  const int i = blockIdx.x * blockDim.x + threadIdx.x;  // 0..2097151
  const float* src;
  bf16* dst;
  int k;
  if (i < 1048576) {
    src = x; dst = xb; k = i;
  } else if (i < 1048576 + 786432) {
    src = qw; dst = qwb; k = i - 1048576;
  } else {
    src = ow; dst = owb; k = i - (1048576 + 786432);
  }
  const float4 v = ((const float4*)src)[k];
  bf16x4 o;
  o[0] = (bf16)v.x; o[1] = (bf16)v.y; o[2] = (bf16)v.z; o[3] = (bf16)v.w;
  ((bf16x4*)dst)[k] = o;
}

// QKV GEMM, 16x16 MFMA + XOR chunk-swizzled LDS.
// r17 evidence: SQ_LDS_BANK_CONFLICT=2.2e7 (~62% of cycles) — 128B rows put a
// quad's 16 fragment-read lanes on one 4-bank chunk. Swizzle: physical chunk p
// of row r holds logical chunk p^(r&7). Producer free (DMA dest unchanged;
// per-lane global source col permuted within the row — same cache lines).
// Consumer: quad's lanes spread over all 8 chunks -> 2 lanes/chunk = free.
//   col<1024  -> Qb[t][col], PRE-SCALED by 0.125*log2(e)
//   col<2048  -> KF fragment-native (attn A-frag = base + lane*16B)
//   col>=2048 -> VF fragment-native, bf16x4-packed along t
__global__ __launch_bounds__(256, 2) void gemm_qkv(
    const bf16* __restrict__ A, const bf16* __restrict__ B,
    const float* __restrict__ bias, bf16* __restrict__ Qb,
    bf16* __restrict__ KF, bf16* __restrict__ VF) {
  const int K = 1024;
  __shared__ bf16 As[128][64];
  __shared__ bf16 Bs[128][64];
  const int tid = threadIdx.x;
  const int w = tid >> 6, lane = tid & 63;
  const int l15 = lane & 15, quad = lane >> 4;
  const int lr = lane >> 3;  // row within 8-row DMA chunk (= actual_row & 7)
  const int lcs = ((lane & 7) ^ lr) * 8;  // swizzled source col for DMA
  const int sw = l15 & 7;                 // fragment-row & 7 for read side
  const int blk = blockIdx.x;             // 0..767 linear
  const int xslot = blk & 7, rest = blk >> 3;  // rest 0..95
  const int bm = xslot * 4 + (rest & 3);       // 0..31
  const int bn = rest >> 2;                    // 0..23
  const int wm = (w >> 1) * 64, wn = (w & 1) * 64;

  const bf16* Abase = A + (size_t)(bm * 128) * K;
  const bf16* Bbase = B + (size_t)(bn * 128) * K;

  f32x4 acc[4][4] = {};

  for (int k0 = 0; k0 < K; k0 += 64) {
#pragma unroll
    for (int c = 0; c < 4; ++c) {
      const int row = w * 32 + c * 8;  // ≡0 mod 8 -> (row+lr)&7 == lr
      lds_load16(&As[row][0], Abase + (size_t)(row + lr) * K + k0 + lcs);
      lds_load16(&Bs[row][0], Bbase + (size_t)(row + lr) * K + k0 + lcs);
    }
    __syncthreads();
#pragma unroll
    for (int kk = 0; kk < 64; kk += 32) {
      const int cb = kk >> 3;  // logical chunk base: 0 or 4
      bf16x8 am[4], bnf[4];
#pragma unroll
      for (int i = 0; i < 4; ++i)
        am[i] = *(const bf16x8*)&As[wm + i * 16 + l15][((cb + quad) ^ sw) * 8];
#pragma unroll
      for (int j = 0; j < 4; ++j)
        bnf[j] = *(const bf16x8*)&Bs[wn + j * 16 + l15][((cb + quad) ^ sw) * 8];
#pragma unroll
      for (int i = 0; i < 4; ++i)
#pragma unroll
        for (int j = 0; j < 4; ++j)
          acc[i][j] = MFMA16(am[i], bnf[j], acc[i][j]);
    }
    __syncthreads();
  }

  // epilogue: C/D layout col=lane&15, row=quad*4+reg
#pragma unroll
  for (int j = 0; j < 4; ++j) {
    const int gcol = bn * 128 + wn + j * 16 + l15;
    const float bv = bias[gcol];
#pragma unroll
    for (int i = 0; i < 4; ++i) {
      const int t0 = bm * 128 + wm + i * 16 + quad * 4;  // r-consecutive rows
      if (gcol < 1024) {
#pragma unroll
        for (int r = 0; r < 4; ++r)
          Qb[(size_t)(t0 + r) * 1024 + gcol] =
              (bf16)((acc[i][j][r] + bv) * 0.18033688f);  // 0.125*log2e
      } else if (gcol < 2048) {
        const int dhl = gcol - 1024;  // 0..1023
        const int hh = dhl >> 6, dh = dhl & 63;
        const int tl = t0 & 2047, bb = t0 >> 11;
        const size_t frag = ((size_t)(bb * 16 + hh) * 32 + (tl >> 6)) * 8 +
                            ((tl & 63) >> 4) * 2 + (dh >> 5);
        bf16* p = &KF[frag * 512 +
                      (size_t)(((dh >> 3) & 3) * 16 + (tl & 15)) * 8 + (dh & 7)];
#pragma unroll
        for (int r = 0; r < 4; ++r) p[r * 8] = (bf16)(acc[i][j][r] + bv);
      } else {
        const int dhl = gcol - 2048;
        const int hh = dhl >> 6, dh = dhl & 63;
        const int tl = t0 & 2047, bb = t0 >> 11;
        const size_t frag = ((size_t)(bb * 16 + hh) * 32 + (tl >> 6)) * 8 +
                            (dh >> 4) * 2 + ((tl & 63) >> 5);
        bf16x4 pv;
#pragma unroll
        for (int r = 0; r < 4; ++r) pv[r] = (bf16)(acc[i][j][r] + bv);
        *(bf16x4*)&VF[frag * 512 +
                      (size_t)(((tl & 31) >> 3) * 16 + (dh & 15)) * 8 +
                      (tl & 7)] = pv;
      }
    }
  }
}

// Out-proj GEMM, 64x128 tile, same XOR chunk-swizzle.
__global__ __launch_bounds__(256, 2) void gemm_out(
    const bf16* __restrict__ A, const bf16* __restrict__ B,
    const float* __restrict__ bias, float* __restrict__ Cf) {
  __shared__ bf16 As[64][64];
  __shared__ bf16 Bs[128][64];
  const int tid = threadIdx.x;
  const int w = tid >> 6, lane = tid & 63;
  const int l15 = lane & 15, quad = lane >> 4;
  const int lr = lane >> 3;
  const int lcs = ((lane & 7) ^ lr) * 8;  // swizzled DMA source col
  const int sw = l15 & 7;
  const int blk = blockIdx.x;  // 0..511 linear
  const int xslot = blk & 7, rest = blk >> 3;  // rest 0..63
  const int bm = xslot * 8 + (rest & 7);       // 0..63
  const int bn = rest >> 3;                    // 0..7

  const bf16* Abase = A + (size_t)(bm * 64) * 1024;
  const bf16* Bbase = B + (size_t)(bn * 128) * 1024;

  f32x4 acc[4][2] = {};

  for (int k0 = 0; k0 < 1024; k0 += 64) {
#pragma unroll
    for (int c = 0; c < 2; ++c) {
      const int row = w * 16 + c * 8;
      lds_load16(&As[row][0], Abase + (size_t)(row + lr) * 1024 + k0 + lcs);
    }
#pragma unroll
    for (int c = 0; c < 4; ++c) {
      const int row = w * 32 + c * 8;
      lds_load16(&Bs[row][0], Bbase + (size_t)(row + lr) * 1024 + k0 + lcs);
    }
    __syncthreads();
#pragma unroll
    for (int kk = 0; kk < 64; kk += 32) {
      const int cb = kk >> 3;
      bf16x8 am[4], bnf[2];
#pragma unroll
      for (int i = 0; i < 4; ++i)
        am[i] = *(const bf16x8*)&As[i * 16 + l15][((cb + quad) ^ sw) * 8];
#pragma unroll
      for (int j = 0; j < 2; ++j)
        bnf[j] =
            *(const bf16x8*)&Bs[w * 32 + j * 16 + l15][((cb + quad) ^ sw) * 8];
#pragma unroll
      for (int i = 0; i < 4; ++i)
#pragma unroll
        for (int j = 0; j < 2; ++j)
          acc[i][j] = MFMA16(am[i], bnf[j], acc[i][j]);
    }
    __syncthreads();
  }

#pragma unroll
  for (int j = 0; j < 2; ++j) {
    const int gcol = bn * 128 + w * 32 + j * 16 + l15;
    const float bv = bias[gcol];
#pragma unroll
    for (int i = 0; i < 4; ++i)
#pragma unroll
      for (int r = 0; r < 4; ++r) {
        const int grow = bm * 64 + i * 16 + quad * 4 + r;
        Cf[(size_t)grow * 1024 + gcol] = acc[i][j][r] + bv;
      }
  }
}

// Flash attention v9 (FROZEN — structural plateau at ~52 us).
__global__ __launch_bounds__(256, 2) void attn(const bf16* __restrict__ Qb,
                                               const bf16* __restrict__ KF,
                                               const bf16* __restrict__ VF,
                                               bf16* __restrict__ CTX) {
  __shared__ bf16 Kb[2][4096];  // ping-pong K fragment tiles (8 KB each)
  __shared__ bf16 Vb[2][4096];  // ping-pong V fragment tiles
  __shared__ bf16 Ps[128][72];  // [q][key], wave-private 32-row bands
  const int tid = threadIdx.x, w = tid >> 6, lane = tid & 63;
  const int l15 = lane & 15, quad = lane >> 4;
  const int blk = blockIdx.x;
  const int slot = blk & 7, grp = blk >> 3;
  const int qt = grp & 15, bh = (grp >> 4) * 8 + slot;  // bh 0..31
  const int h = bh & 15, b = bh >> 4;
  const int q0 = qt * 128;

  const bf16* qrow0 =
      Qb + (size_t)(b * 2048 + q0 + w * 32 + l15) * 1024 + h * 64;
  const bf16* qrow1 = qrow0 + (size_t)16 * 1024;
  const bf16x8 bq0a = *(const bf16x8*)&qrow0[quad * 8];
  const bf16x8 bq0b = *(const bf16x8*)&qrow0[32 + quad * 8];
  const bf16x8 bq1a = *(const bf16x8*)&qrow1[quad * 8];
  const bf16x8 bq1b = *(const bf16x8*)&qrow1[32 + quad * 8];

  const bf16* kfs = KF + (size_t)(b * 16 + h) * 131072;
  const bf16* vfs = VF + (size_t)(b * 16 + h) * 131072;
  const int so = w * 1024;

#pragma unroll
  for (int c = 0; c < 2; ++c) {
    lds_load16(&Kb[0][so + c * 512], kfs + so + c * 512 + lane * 8);
    lds_load16(&Vb[0][so + c * 512], vfs + so + c * 512 + lane * 8);
  }

  float l_run[2] = {0.f, 0.f};
  f32x4 o[2][4] = {};

  for (int kt6 = 0; kt6 < 32; ++kt6) {
    const int cur = kt6 & 1;
    const bf16* kcur = Kb[cur];
    const bf16* vcur = Vb[cur];
    __syncthreads();

    if (kt6 < 31) {
      const size_t nb = (size_t)(kt6 + 1) * 4096;
#pragma unroll
      for (int c = 0; c < 2; ++c) {
        lds_load16(&Kb[cur ^ 1][so + c * 512], kfs + nb + so + c * 512 + lane * 8);
        lds_load16(&Vb[cur ^ 1][so + c * 512], vfs + nb + so + c * 512 + lane * 8);
      }
    }

    f32x4 s[2][4] = {};
#pragma unroll
    for (int k2 = 0; k2 < 2; ++k2)
#pragma unroll
      for (int j = 0; j < 4; ++j) {
        const bf16x8 ak = *(const bf16x8*)&kcur[(j * 2 + k2) * 512 + lane * 8];
        s[0][j] = MFMA16(ak, k2 ? bq0b : bq0a, s[0][j]);
        s[1][j] = MFMA16(ak, k2 ? bq1b : bq1a, s[1][j]);
      }

#pragma unroll
    for (int i = 0; i < 2; ++i) {
      float sum = 0.f;
#pragma unroll
      for (int j = 0; j < 4; ++j) {
        bf16x4 pk;
#pragma unroll
        for (int r = 0; r < 4; ++r) {
          const float p = __builtin_amdgcn_exp2f(s[i][j][r]);
          sum += p;
          pk[r] = (bf16)p;
        }
        *(bf16x4*)&Ps[w * 32 + i * 16 + l15][j * 16 + quad * 4] = pk;
      }
      l_run[i] += sum;
    }

#pragma unroll
    for (int k2 = 0; k2 < 2; ++k2) {
      const bf16x8 bp0 = *(const bf16x8*)&Ps[w * 32 + l15][k2 * 32 + quad * 8];
      const bf16x8 bp1 =
          *(const bf16x8*)&Ps[w * 32 + 16 + l15][k2 * 32 + quad * 8];
#pragma unroll
      for (int j = 0; j < 4; ++j) {
        const bf16x8 av = *(const bf16x8*)&vcur[(j * 2 + k2) * 512 + lane * 8];
        o[0][j] = MFMA16(av, bp0, o[0][j]);
        o[1][j] = MFMA16(av, bp1, o[1][j]);
      }
    }
  }

#pragma unroll
  for (int i = 0; i < 2; ++i) {
    l_run[i] += __shfl_xor(l_run[i], 16);
    l_run[i] += __shfl_xor(l_run[i], 32);
  }

#pragma unroll
  for (int i = 0; i < 2; ++i) {
    const float inv = 1.f / l_run[i];
    bf16* crow =
        CTX + (size_t)(b * 2048 + q0 + w * 32 + i * 16 + l15) * 1024 + h * 64;
#pragma unroll
    for (int j = 0; j < 4; ++j) {
      bf16x4 ov;
#pragma unroll
      for (int r = 0; r < 4; ++r) ov[r] = (bf16)(o[i][j][r] * inv);
      *(bf16x4*)&crow[j * 16 + quad * 4] = ov;
    }
  }
}

extern "C" void kernel_launch(void* const* d_in, const int* in_sizes, int n_in,
                              void* d_out, int out_size, void* d_ws,
                              size_t ws_size, hipStream_t stream) {
  const float* x = (const float*)d_in[0];      // [2,2048,1024] fp32
  const float* qkv_w = (const float*)d_in[1];  // [3072,1024] fp32
  const float* qkv_b = (const float*)d_in[2];  // [3072] fp32
  const float* out_w = (const float*)d_in[3];  // [1024,1024] fp32
  const float* out_b = (const float*)d_in[4];  // [1024] fp32
  float* out = (float*)d_out;                  // [2,2048,1024] fp32

  // ws (bf16): xb 8MB | wqkv 6MB | wout 2MB | qb 8 | KF 8 | VF 8 | ctx 8 = 48MB
  bf16* xb = (bf16*)d_ws;                   // [4096][1024]
  bf16* wqkv = xb + (size_t)4096 * 1024;    // [3072][1024]
  bf16* wout = wqkv + (size_t)3072 * 1024;  // [1024][1024]
  bf16* qb = wout + (size_t)1024 * 1024;    // [4096][1024], x0.125*log2e
  bf16* kf = qb + (size_t)4096 * 1024;      // frag-native K
  bf16* vf = kf + (size_t)4096 * 1024;      // frag-native V^T
  bf16* ctx = vf + (size_t)4096 * 1024;     // [4096][1024]

  cvt3<<<2097152 / 256, 256, 0, stream>>>(x, qkv_w, out_w, xb, wqkv, wout);

  gemm_qkv<<<768, 256, 0, stream>>>(xb, wqkv, qkv_b, qb, kf, vf);
  attn<<<512, 256, 0, stream>>>(qb, kf, vf, ctx);
  gemm_out<<<512, 256, 0, stream>>>(ctx, wout, out_b, out);
}